// Round 6
// baseline (569.329 us; speedup 1.0000x reference)
//
#include <hip/hip_runtime.h>
#include <hip/hip_bf16.h>

typedef __bf16 bf8_t __attribute__((ext_vector_type(8)));
typedef __bf16 bf4_t __attribute__((ext_vector_type(4)));
typedef float f4_t __attribute__((ext_vector_type(4)));

#define B_ 32
#define T_ 2048
#define C_ 1024
#define H_ 128

// ---------------- W fp32 -> bf16 once, in MFMA-fragment order ----------------
__global__ __launch_bounds__(256) void wconv_kernel(
    const float* __restrict__ Wk, const float* __restrict__ Wq, const float* __restrict__ Wv,
    __bf16* __restrict__ Wr)
{
    const int e  = (blockIdx.x * 256 + threadIdx.x) * 8;   // grid 192 -> 393216 elts
    const int kk = e & 31;                                  // multiple of 8
    const int lr = (e >> 5) & 15;
    const int ks = (e >> 9) & 31;
    const int cg = e >> 14;
    const int col = cg * 16 + lr;
    const int k   = ks * 32 + kk;
    const float* W = (col < 128) ? Wk : (col < 256) ? Wq : Wv;
    const float* p = W + (size_t)(col & 127) * C_ + k;
    float4 f0 = *(const float4*)p;
    float4 f1 = *(const float4*)(p + 4);
    bf8_t o;
    o[0] = (__bf16)f0.x; o[1] = (__bf16)f0.y; o[2] = (__bf16)f0.z; o[3] = (__bf16)f0.w;
    o[4] = (__bf16)f1.x; o[5] = (__bf16)f1.y; o[6] = (__bf16)f1.z; o[7] = (__bf16)f1.w;
    *(bf8_t*)(Wr + e) = o;
}

// ---------------- projection: m97-style 2-phase 128x128 GEMM tiles -----------
// Same verified main loop as R3-R5; epilogue now stores K/Q/V in MFMA-fragment
// order so flash can stream operands from L2 with contiguous 1KB blocks:
//  KF/QF: [b][j=t/64][s16=(t%64)/16][ks=h/32] 512-elt block @ (t%16)*32+(h%32)
//  VF:    [b][j=tok/64][nh=h/16][ks2=(tok%64)/32] block @ (h%16)*32+(tok%32)
__global__ __launch_bounds__(256) void proj_kernel(
    const float* __restrict__ x, const __bf16* __restrict__ Wr,
    __bf16* __restrict__ KF, __bf16* __restrict__ QF, __bf16* __restrict__ VF)
{
    __shared__ __bf16 As[128 * 64];      // 16 KB, row=64 units, XOR-swizzled
    __shared__ __bf16 Bs[2][16 * 512];   // 2 x 16 KB, 16 fragment chunks each

    const int bid  = blockIdx.x;
    const int xcd  = bid & 7;
    const int slot = bid >> 3;
    const int nt   = slot % 3;                 // 0:K 1:Q 2:V
    const int m0   = ((slot / 3) * 8 + xcd) * 128;
    const int tid  = threadIdx.x;
    const int lane = tid & 63;
    const int w    = tid >> 6;
    const int wqm  = w >> 1;
    const int wqn  = w & 1;
    const int lr   = lane & 15;
    const int quad = lane >> 4;

    f4_t acc[4][4];
    #pragma unroll
    for (int mi = 0; mi < 4; mi++)
        #pragma unroll
        for (int ni = 0; ni < 4; ni++) acc[mi][ni] = f4_t{0.f, 0.f, 0.f, 0.f};

    float4 pf[8];

#define LOADA(t) { _Pragma("unroll") \
    for (int i_ = 0; i_ < 8; ++i_) { \
        const int u_ = i_ * 256 + tid; \
        pf[i_] = *(const float4*)(x + (size_t)(m0 + (u_ >> 4)) * C_ + (t) * 64 + (u_ & 15) * 4); } }

#define WRITEA { _Pragma("unroll") \
    for (int i_ = 0; i_ < 8; ++i_) { \
        const int u_ = i_ * 256 + tid; \
        const int r_ = u_ >> 4; \
        float4 f_ = pf[i_]; \
        *(bf4_t*)&As[r_ * 64 + ((((u_ & 15) * 4)) ^ ((r_ & 7) * 8))] = \
            bf4_t{(__bf16)f_.x, (__bf16)f_.y, (__bf16)f_.z, (__bf16)f_.w}; } }

#define STAGEB(t, bsel) { _Pragma("unroll") \
    for (int i_ = 0; i_ < 4; ++i_) { \
        const int ci_ = i_ * 4 + w; \
        const __bf16* src_ = Wr + ((size_t)((nt * 8 + (ci_ >> 1)) * 32 + (t) * 2 + (ci_ & 1)) << 9) + lane * 8; \
        __builtin_amdgcn_global_load_lds( \
            (const __attribute__((address_space(1))) void*)src_, \
            (__attribute__((address_space(3))) void*)&Bs[bsel][ci_ << 9], 16, 0, 0); } }

    LOADA(0)
    STAGEB(0, 0)
    WRITEA
    __syncthreads();

    #pragma unroll 2
    for (int t = 0; t < 16; ++t) {
        const int bsel = t & 1;
        if (t < 15) {
            LOADA(t + 1)
            STAGEB(t + 1, bsel ^ 1)
        }
        #pragma unroll
        for (int kh = 0; kh < 2; ++kh) {
            bf8_t af[4], bfr[4];
            #pragma unroll
            for (int mi = 0; mi < 4; ++mi) {
                const int row = wqm * 64 + mi * 16 + lr;
                af[mi] = *(const bf8_t*)&As[row * 64 + ((kh * 32 + quad * 8) ^ ((row & 7) * 8))];
            }
            #pragma unroll
            for (int ni = 0; ni < 4; ++ni) {
                const int ch = (wqn * 4 + ni) * 2 + kh;
                bfr[ni] = *(const bf8_t*)&Bs[bsel][ch * 512 + lr * 32 + quad * 8];
            }
            if (nt < 2) {
                #pragma unroll
                for (int mi = 0; mi < 4; ++mi)
                    #pragma unroll
                    for (int ni = 0; ni < 4; ++ni)
                        acc[mi][ni] = __builtin_amdgcn_mfma_f32_16x16x32_bf16(af[mi], bfr[ni], acc[mi][ni], 0, 0, 0);
            } else {
                #pragma unroll
                for (int mi = 0; mi < 4; ++mi)
                    #pragma unroll
                    for (int ni = 0; ni < 4; ++ni)
                        acc[mi][ni] = __builtin_amdgcn_mfma_f32_16x16x32_bf16(bfr[ni], af[mi], acc[mi][ni], 0, 0, 0);
            }
        }
        __syncthreads();
        if (t < 15) {
            WRITEA
            __syncthreads();
        }
    }

#undef LOADA
#undef WRITEA
#undef STAGEB

    if (nt < 2) {
        __bf16* OutF = nt ? QF : KF;
        #pragma unroll
        for (int ni = 0; ni < 4; ++ni) {
            const int col = wqn * 64 + ni * 16 + lr;
            const int ks  = col >> 5;
            const int kk  = col & 31;
            #pragma unroll
            for (int mi = 0; mi < 4; ++mi)
                #pragma unroll
                for (int r = 0; r < 4; ++r) {
                    const int row = m0 + wqm * 64 + mi * 16 + quad * 4 + r;
                    const int bb2 = row >> 11, t2 = row & 2047;
                    OutF[((((size_t)bb2 * 32 + (t2 >> 6)) * 4 + ((t2 >> 4) & 3)) * 4 + ks) * 512
                         + (t2 & 15) * 32 + kk] = (__bf16)acc[mi][ni][r];
                }
        }
    } else {
        const int bb = m0 >> 11;
        const int t0 = m0 & (T_ - 1);
        #pragma unroll
        for (int ni = 0; ni < 4; ++ni)
            #pragma unroll
            for (int mi = 0; mi < 4; ++mi) {
                const int tok = t0 + wqm * 64 + mi * 16 + lr;
                #pragma unroll
                for (int r = 0; r < 4; ++r) {
                    const int h = wqn * 64 + ni * 16 + quad * 4 + r;
                    VF[((((size_t)bb * 32 + (tok >> 6)) * 8 + (h >> 4)) * 2 + ((tok & 63) >> 5)) * 512
                       + (h & 15) * 32 + (tok & 31)] = (__bf16)acc[mi][ni][r];
                }
            }
    }
}

// ---------------- flash attention v4: barrier-free, L2-streamed K/V ----------
// grid 1024 = 32 batches x 32 q-tiles (64 rows). 4 waves x 16 q-rows; all
// operands read as contiguous 1KB MFMA fragments straight from L2 (KF/QF/VF
// written by proj). NO __syncthreads, no K/V LDS: waves fully independent;
// only wave-private Ps slab in LDS (lgkm-ordered). bid%8 = batch%8 pins each
// batch's 1.5 MB working set to one XCD's L2. qt<->slot map makes each CU's
// 4 resident blocks sum to exactly 66 rounds (balanced, no drain tail).
__global__ __launch_bounds__(256, 4) void flash_kernel(
    const __bf16* __restrict__ QF, const __bf16* __restrict__ KF,
    const __bf16* __restrict__ VF, float* __restrict__ Out)
{
    __shared__ __bf16 Ps[64][72];    // [q][s], wave-private 16-row slabs

    const int bid = blockIdx.x;
    const int b   = bid & 31;        // batch (bid%8 = b%8 -> XCD locality)
    const int s   = bid >> 5;        // 0..31
    // octet-balanced qt map: CU's residents {31-a, 16+a, 15-a, a} -> 66 rounds
    const int qt  = (s < 8) ? (31 - s) : (s < 16) ? (s + 8) : (s < 24) ? (31 - s) : (s - 24);

    const int tid  = threadIdx.x;
    const int lane = tid & 63;
    const int w    = tid >> 6;       // 0..3
    const int lr   = lane & 15;
    const int quad = lane >> 4;
    const int fo   = lr * 32 + quad * 8;   // intra-fragment offset

    const float sc = 0.03125f * 1.4426950408889634f;   // C^-0.5 * log2(e)
    const int jmax = qt;

    // Q fragments (B-operand of swapped QK^T)
    bf8_t qf[4];
    {
        const __bf16* qp = QF + (((size_t)(b * 32 + qt) * 4 + w) * 4) * 512 + fo;
        #pragma unroll
        for (int ks = 0; ks < 4; ks++) qf[ks] = *(const bf8_t*)(qp + ks * 512);
    }

    f4_t o[8];
    #pragma unroll
    for (int n = 0; n < 8; n++) o[n] = f4_t{0.f, 0.f, 0.f, 0.f};
    float ls = 0.f;

    for (int j = 0; j <= jmax; ++j) {
        const __bf16* kb = KF + ((size_t)(b * 32 + j) * 16) * 512 + fo;
        const __bf16* vb = VF + ((size_t)(b * 32 + j) * 16) * 512 + fo;

        // QK^T swapped: s4[n][r] = S[k = j*64+n*16+quad*4+r][q = qt*64+w*16+lr]
        f4_t s4[4];
        #pragma unroll
        for (int n = 0; n < 4; n++) s4[n] = f4_t{0.f, 0.f, 0.f, 0.f};
        #pragma unroll
        for (int ks = 0; ks < 4; ks++)
            #pragma unroll
            for (int n = 0; n < 4; n++) {
                bf8_t kf = *(const bf8_t*)(kb + (n * 4 + ks) * 512);
                s4[n] = __builtin_amdgcn_mfma_f32_16x16x32_bf16(kf, qf[ks], s4[n], 0, 0, 0);
            }

        // softmax (per-lane single q-row) + packed P write to wave-private slab
        const bool dm = (j == jmax);
        const int qg = w * 16 + lr;
        #pragma unroll
        for (int n = 0; n < 4; n++) {
            bf4_t pk;
            #pragma unroll
            for (int r = 0; r < 4; r++) {
                float p = __builtin_exp2f(s4[n][r] * sc);
                if (dm && (n * 16 + quad * 4 + r) > qg) p = 0.f;
                ls += p;
                pk[r] = (__bf16)p;
            }
            *(bf4_t*)&Ps[w * 16 + lr][n * 16 + quad * 4] = pk;
        }

        // PV: o[n] += P * V (vf fragments streamed from L2)
        #pragma unroll
        for (int ks = 0; ks < 2; ks++) {
            bf8_t pfr = *(const bf8_t*)&Ps[w * 16 + lr][ks * 32 + quad * 8];
            #pragma unroll
            for (int n = 0; n < 8; n++) {
                bf8_t vf = *(const bf8_t*)(vb + (n * 2 + ks) * 512);
                o[n] = __builtin_amdgcn_mfma_f32_16x16x32_bf16(pfr, vf, o[n], 0, 0, 0);
            }
        }
    }

    // rowsum inverse: lane holds partial for q-row lr; reduce over quads
    float v = ls;
    v += __shfl_xor(v, 16);
    v += __shfl_xor(v, 32);
    const float iv = 1.f / v;
    float inv[4];
    #pragma unroll
    for (int r = 0; r < 4; r++) inv[r] = __shfl(iv, quad * 4 + r);

    const size_t obase = (size_t)b * T_ * H_;
    #pragma unroll
    for (int n = 0; n < 8; n++) {
        const int col = n * 16 + lr;
        #pragma unroll
        for (int r = 0; r < 4; r++) {
            const int row = qt * 64 + w * 16 + quad * 4 + r;
            Out[obase + (size_t)row * H_ + col] = o[n][r] * inv[r];
        }
    }
}

extern "C" void kernel_launch(void* const* d_in, const int* in_sizes, int n_in,
                              void* d_out, int out_size, void* d_ws, size_t ws_size,
                              hipStream_t stream) {
    const float* x  = (const float*)d_in[0];
    const float* Wk = (const float*)d_in[1];
    const float* Wq = (const float*)d_in[2];
    const float* Wv = (const float*)d_in[3];
    float* out = (float*)d_out;

    const size_t n_kqv = (size_t)B_ * T_ * H_;
    __bf16* KF = (__bf16*)d_ws;
    __bf16* QF = KF + n_kqv;
    __bf16* VF = QF + n_kqv;
    __bf16* Wr = VF + n_kqv;   // 768 KB more

    wconv_kernel<<<dim3(192), 256, 0, stream>>>(Wk, Wq, Wv, Wr);
    proj_kernel<<<dim3(512 * 3), 256, 0, stream>>>(x, Wr, KF, QF, VF);
    flash_kernel<<<dim3(1024), 256, 0, stream>>>(QF, KF, VF, out);
}